// Round 2
// baseline (113.625 us; speedup 1.0000x reference)
//
#include <hip/hip_runtime.h>
#include <math.h>

#define BB 256
#define DD 128
#define CC 8000
#define EPSF 1e-12f
#define SCALEF 64.0f
#define MARGINF 0.5f

// ---------------------------------------------------------------------------
// Single fused kernel. Grid 32(c) x 16(r) = 512 blocks x 256 thr
// (2 blocks/CU via __launch_bounds__(256,2), 8 waves/CU).
//   phase 1: local prep into LDS — normalize 16 embds rows (neS), gather+
//            normalize 16 label columns of w (gS), s1 per row.
//   phase 2: dual GEMM over d streaming w (float4, L2-resident). Column
//            norms accumulated for free from the same streamed values.
//   phase 3: penalties written final; e = exp(64*cos) KEPT IN REGISTERS
//            (eo[4][4]); per-(row,cblock) partial sums stored to psums
//            with agent-scope stores.
//   barrier: per-ROW-GROUP (the 32 blocks sharing blockIdx.y) via a
//            monotonic __device__ counter — no init needed (module-load
//            zeroed; launches are stream-serialized so each launch's
//            arrivals are a contiguous [32k, 32k+32) window). Only 32
//            peers must co-reside => safe subset of the 2-blocks/CU grid.
//            Release/acquire expressed ON the atomic ops (this ROCm has no
//            __hip_atomic_fence).
//   tail:    gather the 32 psums/row (agent-scope loads), inv = 1/sum,
//            scale register eo, single normalized logits write. The old
//            scale_kernel (8.2 MB HBM read + 8.2 MB rewrite + a launch)
//            is gone.
// ---------------------------------------------------------------------------

// 16 row-group counters, padded to 64 B each to avoid one hot cacheline.
__device__ int g_arrive[16 * 16];  // static storage: zero at module load

__global__ __launch_bounds__(256, 2) void fused_kernel(
    const float* __restrict__ embds, const float* __restrict__ w,
    const int* __restrict__ labels, float* __restrict__ out,
    float* __restrict__ psums) {
  __shared__ float neS[DD * 16];
  __shared__ float gS[DD * 16];
  __shared__ float s1S[16];
  __shared__ float invS[16];
  __shared__ int labS[16];

  int tid = threadIdx.x;
  int c0 = blockIdx.x * 256;
  int r0 = blockIdx.y * 16;

  // ---- phase 1: local prep (16 rows x 16 threads each) ----
  {
    int r = tid >> 4;           // 0..15 local row
    int k = tid & 15;           // 0..15, each handles 8 d's
    int row = r0 + r;
    int lab = labels[row];
    const float4* e4 = (const float4*)(embds + row * DD + k * 8);
    float4 ea = e4[0], eb = e4[1];
    float ev[8] = {ea.x, ea.y, ea.z, ea.w, eb.x, eb.y, eb.z, eb.w};
    float wl[8];
    float se = 0.f, sw = 0.f, sx = 0.f;
    #pragma unroll
    for (int i = 0; i < 8; ++i) {
      wl[i] = w[(k * 8 + i) * CC + lab];
      se = fmaf(ev[i], ev[i], se);
      sw = fmaf(wl[i], wl[i], sw);
      sx = fmaf(ev[i], wl[i], sx);
    }
    // reduce within the 16-lane k-group (xor masks 1,2,4,8 stay in-group)
    #pragma unroll
    for (int off = 1; off < 16; off <<= 1) {
      se += __shfl_xor(se, off, 64);
      sw += __shfl_xor(sw, off, 64);
      sx += __shfl_xor(sx, off, 64);
    }
    float rn = rsqrtf(fmaxf(se, EPSF));
    float rl = rsqrtf(fmaxf(sw, EPSF));
    #pragma unroll
    for (int i = 0; i < 8; ++i) {
      neS[(k * 8 + i) * 16 + r] = ev[i] * rn;
      gS[(k * 8 + i) * 16 + r] = wl[i] * rl;
    }
    if (k == 0) { s1S[r] = sx * rn * rl; labS[r] = lab; }
  }
  __syncthreads();

  // ---- phase 2: dual GEMM, w streamed once per block ----
  int tx = tid & 63;
  int ty = tid >> 6;            // wave id = row group (wave-uniform)
  int c = c0 + tx * 4;
  bool cok = c < CC;
  const float4* w4 = (const float4*)w;
  int wbase = (c0 >> 2) + tx;

  float accC[4][4], accG[4][4], colsum[4];
  #pragma unroll
  for (int rr = 0; rr < 4; ++rr)
    #pragma unroll
    for (int j = 0; j < 4; ++j) { accC[rr][j] = 0.f; accG[rr][j] = 0.f; }
  #pragma unroll
  for (int j = 0; j < 4; ++j) colsum[j] = 0.f;

  #pragma unroll 8
  for (int d = 0; d < DD; ++d) {
    float4 wv = cok ? w4[d * (CC / 4) + wbase] : make_float4(0.f, 0.f, 0.f, 0.f);
    float4 a = *(const float4*)&neS[d * 16 + ty * 4];  // wave-uniform: broadcast
    float4 g = *(const float4*)&gS[d * 16 + ty * 4];
    float av[4] = {a.x, a.y, a.z, a.w};
    float gv[4] = {g.x, g.y, g.z, g.w};
    float wj[4] = {wv.x, wv.y, wv.z, wv.w};
    #pragma unroll
    for (int j = 0; j < 4; ++j) colsum[j] = fmaf(wj[j], wj[j], colsum[j]);
    #pragma unroll
    for (int rr = 0; rr < 4; ++rr) {
      #pragma unroll
      for (int j = 0; j < 4; ++j) {
        accC[rr][j] = fmaf(av[rr], wj[j], accC[rr][j]);
        accG[rr][j] = fmaf(gv[rr], wj[j], accG[rr][j]);
      }
    }
  }

  // ---- phase 3: penalties (final) + e-values in regs + psum partials ----
  float rcj[4];
  #pragma unroll
  for (int j = 0; j < 4; ++j) rcj[j] = rsqrtf(fmaxf(colsum[j], EPSF));

  float* pen_base = out + (size_t)BB * CC;
  float eo[4][4];
  #pragma unroll
  for (int rr = 0; rr < 4; ++rr) {
    int lr = ty * 4 + rr;
    int row = r0 + lr;
    float s1v = s1S[lr];
    int lab = labS[lr];
    float penv[4];
    float psum = 0.f;
    #pragma unroll
    for (int j = 0; j < 4; ++j) {
      float cs = accC[rr][j] * rcj[j];
      float gw = accG[rr][j] * rcj[j];
      float win = (s1v - cs) * rsqrtf(fmaxf(2.f - 2.f * gw, EPSF));
      if (c + j == lab) win = 0.f;
      penv[j] = MARGINF - fminf(MARGINF, win);
      float e = cok ? __expf(SCALEF * cs) : 0.f;
      eo[rr][j] = e;
      psum += e;
    }
    if (cok) {
      size_t o4 = (size_t)row * (CC / 4) + wbase;
      ((float4*)pen_base)[o4] = make_float4(penv[0], penv[1], penv[2], penv[3]);
    }
    // wave reduction of psum (all 64 lanes, this row)
    #pragma unroll
    for (int off = 1; off < 64; off <<= 1) psum += __shfl_xor(psum, off, 64);
    if (tx == 0)
      __hip_atomic_store(&psums[row * 32 + blockIdx.x], psum,
                         __ATOMIC_RELAXED, __HIP_MEMORY_SCOPE_AGENT);
  }

  __syncthreads();  // drains vmem: all psums stores of this block issued+done

  // ---- per-row-group device barrier (32 peer blocks, same blockIdx.y) ----
  if (tid == 0) {
    int* ctr = &g_arrive[blockIdx.y * 16];
    // RELEASE on the add: orders this block's psums stores before the bump.
    int old = __hip_atomic_fetch_add(ctr, 1, __ATOMIC_RELEASE,
                                     __HIP_MEMORY_SCOPE_AGENT);
    // launches are serialized on the stream, so this launch's window is
    // [32k, 32k+32): every peer computes the same target.
    int target = ((old >> 5) << 5) + 32;
    int guard = 0;
    // ACQUIRE on the poll: synchronizes-with every peer's release add.
    while (__hip_atomic_load(ctr, __ATOMIC_ACQUIRE,
                             __HIP_MEMORY_SCOPE_AGENT) < target &&
           ++guard < (1 << 22)) {  // bounded: fail loud, never hang
      __builtin_amdgcn_s_sleep(4);
    }
  }
  __syncthreads();

  // ---- gather the 32 psums per row -> invS ----
  {
    int lr = tid >> 4;                 // local row 0..15
    int jj = (tid & 15) * 2;           // pair of col-block partials
    float* pr = psums + (size_t)(r0 + lr) * 32 + jj;
    float p2 =
        __hip_atomic_load(&pr[0], __ATOMIC_RELAXED, __HIP_MEMORY_SCOPE_AGENT) +
        __hip_atomic_load(&pr[1], __ATOMIC_RELAXED, __HIP_MEMORY_SCOPE_AGENT);
    #pragma unroll
    for (int off = 1; off < 16; off <<= 1) p2 += __shfl_xor(p2, off, 64);
    if ((tid & 15) == 0) invS[lr] = 1.f / p2;
  }
  __syncthreads();

  // ---- normalized logits write (from registers — no HBM round trip) ----
  if (cok) {
    #pragma unroll
    for (int rr = 0; rr < 4; ++rr) {
      int lr = ty * 4 + rr;
      int row = r0 + lr;
      float inv = invS[lr];
      size_t o4 = (size_t)row * (CC / 4) + wbase;
      ((float4*)out)[o4] = make_float4(eo[rr][0] * inv, eo[rr][1] * inv,
                                       eo[rr][2] * inv, eo[rr][3] * inv);
    }
  }
}

extern "C" void kernel_launch(void* const* d_in, const int* in_sizes, int n_in,
                              void* d_out, int out_size, void* d_ws, size_t ws_size,
                              hipStream_t stream) {
  const float* embds = (const float*)d_in[0];
  const float* w = (const float*)d_in[1];
  const int* labels = (const int*)d_in[2];
  float* out = (float*)d_out;
  float* psums = (float*)d_ws;    // [256][32]

  dim3 gA(32, 16);
  fused_kernel<<<gA, 256, 0, stream>>>(embds, w, labels, out, psums);
}

// Round 3
// 96.330 us; speedup vs baseline: 1.1795x; 1.1795x over previous
//
#include <hip/hip_runtime.h>
#include <math.h>

#define BB 256
#define DD 128
#define CC 8000
#define EPSF 1e-12f
#define SCALEF 64.0f
#define MARGINF 0.5f

// ---------------------------------------------------------------------------
// Kernel A: fused prep + dual GEMM + epilogue.
// Grid 32(c) x 32(r) = 1024 blocks x 256 thr -> 4 blocks/CU, 16 waves/CU.
// (Round-2 postmortem: 2 blocks/CU was latency-bound — VALUBusy 18%,
//  HBM 5%, Occupancy 17.5%. Cross-block barrier reverted: cost ~20us in
//  cross-XCD coherence + peer-wait, more than the scale_kernel it saved.)
//   phase 1: normalize 8 embds rows + gather/normalize 8 label cols into
//            LDS (row-major [8][128]: phase-2 reads are wave-uniform
//            float4 broadcasts, conflict-free).
//   phase 2: dual GEMM over d in chunks of 4, software-pipelined: next
//            chunk's 4 w-float4 loads issued before current chunk's 80
//            FMAs. Column norms accumulated for free.
//   phase 3: penalties final; e = exp(64*cos) unnormalized to logits
//            region (arg<=64 fits fp32); per-(row,cblock) psums, no
//            atomics.
// ---------------------------------------------------------------------------
__global__ __launch_bounds__(256, 4) void fused_kernel(
    const float* __restrict__ embds, const float* __restrict__ w,
    const int* __restrict__ labels, float* __restrict__ out,
    float* __restrict__ psums) {
  __shared__ float neS[8][DD];
  __shared__ float gS[8][DD];
  __shared__ float s1S[8];
  __shared__ int labS[8];

  int tid = threadIdx.x;
  int c0 = blockIdx.x * 256;
  int r0 = blockIdx.y * 8;

  // ---- phase 1: local prep (8 rows x 32 lanes each, 4 d's per lane) ----
  {
    int r = tid >> 5;           // 0..7 local row
    int k = tid & 31;           // 0..31
    int row = r0 + r;
    int lab = labels[row];
    float4 e4 = *(const float4*)(embds + row * DD + k * 4);
    float ev[4] = {e4.x, e4.y, e4.z, e4.w};
    float wl[4];
    float se = 0.f, sw = 0.f, sx = 0.f;
    #pragma unroll
    for (int i = 0; i < 4; ++i) {
      wl[i] = w[(k * 4 + i) * CC + lab];
      se = fmaf(ev[i], ev[i], se);
      sw = fmaf(wl[i], wl[i], sw);
      sx = fmaf(ev[i], wl[i], sx);
    }
    // reduce within the 32-lane k-group (xor masks 1..16 stay in-half)
    #pragma unroll
    for (int off = 1; off < 32; off <<= 1) {
      se += __shfl_xor(se, off, 64);
      sw += __shfl_xor(sw, off, 64);
      sx += __shfl_xor(sx, off, 64);
    }
    float rn = rsqrtf(fmaxf(se, EPSF));
    float rl = rsqrtf(fmaxf(sw, EPSF));
    *(float4*)&neS[r][k * 4] =
        make_float4(ev[0] * rn, ev[1] * rn, ev[2] * rn, ev[3] * rn);
    *(float4*)&gS[r][k * 4] =
        make_float4(wl[0] * rl, wl[1] * rl, wl[2] * rl, wl[3] * rl);
    if (k == 0) { s1S[r] = sx * rn * rl; labS[r] = lab; }
  }
  __syncthreads();

  // ---- phase 2: dual GEMM, w streamed once per block, pipelined ----
  int tx = tid & 63;
  int ty = tid >> 6;            // wave id (wave-uniform)
  int c = c0 + tx * 4;
  bool cok = c < CC;
  const float4* w4 = (const float4*)w;
  int wbase = (c0 >> 2) + tx;
  int row0 = ty * 2;            // this wave's 2 rows

  float accC[2][4], accG[2][4], colsum[4];
  #pragma unroll
  for (int rr = 0; rr < 2; ++rr)
    #pragma unroll
    for (int j = 0; j < 4; ++j) { accC[rr][j] = 0.f; accG[rr][j] = 0.f; }
  #pragma unroll
  for (int j = 0; j < 4; ++j) colsum[j] = 0.f;

  float4 wn[4];
  #pragma unroll
  for (int q = 0; q < 4; ++q)
    wn[q] = cok ? w4[q * (CC / 4) + wbase] : make_float4(0.f, 0.f, 0.f, 0.f);

  #pragma unroll 2
  for (int dc = 0; dc < 32; ++dc) {
    int d = dc * 4;
    float wv[4][4];
    #pragma unroll
    for (int q = 0; q < 4; ++q) {
      wv[q][0] = wn[q].x; wv[q][1] = wn[q].y;
      wv[q][2] = wn[q].z; wv[q][3] = wn[q].w;
    }
    if (dc < 31) {  // prefetch next chunk's w before this chunk's FMAs
      #pragma unroll
      for (int q = 0; q < 4; ++q)
        wn[q] = cok ? w4[(d + 4 + q) * (CC / 4) + wbase]
                    : make_float4(0.f, 0.f, 0.f, 0.f);
    }
    float4 a0 = *(const float4*)&neS[row0][d];      // wave-uniform broadcast
    float4 a1 = *(const float4*)&neS[row0 + 1][d];
    float4 g0 = *(const float4*)&gS[row0][d];
    float4 g1 = *(const float4*)&gS[row0 + 1][d];
    float av[2][4] = {{a0.x, a0.y, a0.z, a0.w}, {a1.x, a1.y, a1.z, a1.w}};
    float gv[2][4] = {{g0.x, g0.y, g0.z, g0.w}, {g1.x, g1.y, g1.z, g1.w}};
    #pragma unroll
    for (int q = 0; q < 4; ++q)
      #pragma unroll
      for (int j = 0; j < 4; ++j)
        colsum[j] = fmaf(wv[q][j], wv[q][j], colsum[j]);
    #pragma unroll
    for (int rr = 0; rr < 2; ++rr)
      #pragma unroll
      for (int q = 0; q < 4; ++q)
        #pragma unroll
        for (int j = 0; j < 4; ++j) {
          accC[rr][j] = fmaf(av[rr][q], wv[q][j], accC[rr][j]);
          accG[rr][j] = fmaf(gv[rr][q], wv[q][j], accG[rr][j]);
        }
  }

  // ---- phase 3: epilogue ----
  float rcj[4];
  #pragma unroll
  for (int j = 0; j < 4; ++j) rcj[j] = rsqrtf(fmaxf(colsum[j], EPSF));

  float* pen_base = out + (size_t)BB * CC;
  #pragma unroll
  for (int rr = 0; rr < 2; ++rr) {
    int lr = row0 + rr;
    int row = r0 + lr;
    float s1v = s1S[lr];
    int lab = labS[lr];
    float penv[4], eo[4];
    float psum = 0.f;
    #pragma unroll
    for (int j = 0; j < 4; ++j) {
      float cs = accC[rr][j] * rcj[j];
      float gw = accG[rr][j] * rcj[j];
      float win = (s1v - cs) * rsqrtf(fmaxf(2.f - 2.f * gw, EPSF));
      if (c + j == lab) win = 0.f;
      penv[j] = MARGINF - fminf(MARGINF, win);
      float e = cok ? __expf(SCALEF * cs) : 0.f;
      eo[j] = e;
      psum += e;
    }
    if (cok) {
      size_t o4 = (size_t)row * (CC / 4) + wbase;
      ((float4*)pen_base)[o4] = make_float4(penv[0], penv[1], penv[2], penv[3]);
      ((float4*)out)[o4] = make_float4(eo[0], eo[1], eo[2], eo[3]);
    }
    // wave reduction of psum (all 64 lanes, this row)
    #pragma unroll
    for (int off = 1; off < 64; off <<= 1) psum += __shfl_xor(psum, off, 64);
    if (tx == 0) psums[row * 32 + blockIdx.x] = psum;
  }
}

// ---------------------------------------------------------------------------
// Kernel B: per-row normalize. 256 blocks x 512 thr. Sum the 32 partials,
// scale the row's 8000 unnormalized e-values in place.
// ---------------------------------------------------------------------------
__global__ __launch_bounds__(512) void scale_kernel(
    float* __restrict__ out, const float* __restrict__ psums) {
  __shared__ float invS;
  int r = blockIdx.x;
  int tid = threadIdx.x;
  if (tid < 64) {
    float p = (tid < 32) ? psums[r * 32 + tid] : 0.f;
    #pragma unroll
    for (int off = 1; off < 32; off <<= 1) p += __shfl_xor(p, off, 64);
    if (tid == 0) invS = 1.f / p;
  }
  __syncthreads();
  float inv = invS;
  float4* row = (float4*)out + (size_t)r * (CC / 4);
  #pragma unroll
  for (int k = 0; k < 4; ++k) {
    int i = tid + k * 512;
    if (i < CC / 4) {
      float4 v = row[i];
      row[i] = make_float4(v.x * inv, v.y * inv, v.z * inv, v.w * inv);
    }
  }
}

extern "C" void kernel_launch(void* const* d_in, const int* in_sizes, int n_in,
                              void* d_out, int out_size, void* d_ws, size_t ws_size,
                              hipStream_t stream) {
  const float* embds = (const float*)d_in[0];
  const float* w = (const float*)d_in[1];
  const int* labels = (const int*)d_in[2];
  float* out = (float*)d_out;
  float* psums = (float*)d_ws;    // [256][32]

  dim3 gA(32, 32);
  fused_kernel<<<gA, 256, 0, stream>>>(embds, w, labels, out, psums);
  scale_kernel<<<256, 512, 0, stream>>>(out, psums);
}